// Round 12
// baseline (107.036 us; speedup 1.0000x reference)
//
#include <hip/hip_runtime.h>

#define WINDOW 10
#define TDIM 4096
#define TVALID (TDIM - WINDOW)
#define LROW 4160

typedef __attribute__((ext_vector_type(8)))  short bf16x8;
typedef __attribute__((ext_vector_type(8)))  __bf16 bfv8;
typedef __attribute__((ext_vector_type(8)))  float f32x8;
typedef __attribute__((ext_vector_type(16))) float f32x16;
typedef __attribute__((ext_vector_type(2)))  float f32x2;
typedef float f32x4u __attribute__((ext_vector_type(4), aligned(4)));
typedef float f32x4a __attribute__((ext_vector_type(4), aligned(16)));

static __device__ __forceinline__ short f2bf(float f) {
  return (short)__builtin_bit_cast(unsigned short, (__bf16)f);
}

static __device__ __forceinline__ float combine_halves(float Pe, float Po, int lid) {
#if __has_builtin(__builtin_amdgcn_permlane32_swap)
  auto r = __builtin_amdgcn_permlane32_swap(
      __builtin_bit_cast(unsigned, Pe), __builtin_bit_cast(unsigned, Po), false, false);
  return __builtin_bit_cast(float, (unsigned)r[0]) + __builtin_bit_cast(float, (unsigned)r[1]);
#else
  Pe += __shfl_xor(Pe, 32, 64);
  Po += __shfl_xor(Po, 32, 64);
  return (lid < 32) ? Pe : Po;
#endif
}

static __device__ __forceinline__ float half_sigmoid(float z) {
  float e = __expf(-z);
#if __has_builtin(__builtin_amdgcn_rcpf)
  return 0.5f * __builtin_amdgcn_rcpf(1.0f + e);
#else
  return 0.5f / (1.0f + e);
#endif
}

struct Setup {
  bf16x8 af; f32x16 cinit; f32x2 w2p[8]; float b2c;
  int lid, n, g;
};
static __device__ __forceinline__ Setup make_setup(
    const float* __restrict__ W1, const float* __restrict__ b1,
    const float* __restrict__ W2, const float* __restrict__ b2) {
  Setup s;
  s.lid = threadIdx.x & 63; s.n = s.lid & 31; s.g = s.lid >> 5;
  const bool g1 = (s.g == 1);
  if (!g1) {
    #pragma unroll
    for (int j = 0; j < 8; ++j) s.af[j] = f2bf(W1[s.n * WINDOW + j]);
  } else {
    s.af[0] = f2bf(W1[s.n * WINDOW + 8]);
    s.af[1] = f2bf(W1[s.n * WINDOW + 9]);
    #pragma unroll
    for (int j = 2; j < 8; ++j) s.af[j] = 0;
  }
  #pragma unroll
  for (int r = 0; r < 16; ++r) s.cinit[r] = b1[(r & 3) + 8 * (r >> 2) + 4 * s.g];
  #pragma unroll
  for (int j = 0; j < 8; ++j) {
    s.w2p[j][0] = W2[((2*j)   & 3) + 8 * ((2*j)   >> 2) + 4 * s.g];
    s.w2p[j][1] = W2[((2*j+1) & 3) + 8 * ((2*j+1) >> 2) + 4 * s.g];
  }
  s.b2c = b2[0];
  return s;
}

static __device__ __forceinline__ f32x8 lds_ld8(const float* __restrict__ p) {
  f32x8 f;
  #pragma unroll
  for (int j = 0; j < 8; ++j) f[j] = p[j];
  return f;
}
static __device__ __forceinline__ bf16x8 cvt8(const f32x8& f) {
  return __builtin_bit_cast(bf16x8, __builtin_convertvector(f, bfv8));
}
static __device__ __forceinline__ f32x2 relu2(float x, float y) {
  f32x2 v = {x, y};
  const f32x2 z2 = {0.f, 0.f};
  return __builtin_elementwise_max(v, z2);
}

// ============ calibration: known-cycle dependent-FMA throughput kernel ============
// 2048 blocks x 256 thr -> 8 waves/SIMD. 8192 chained FMAs/lane.
// Throughput-bound: 8 waves * 8192 * 2 cyc = 131072 cycles/SIMD = 54.6 us @ 2.4 GHz.
// Duration directly measures effective clock: f = 2.4 GHz * 54.6 / dur_us.
__global__ __launch_bounds__(256) void k_clock(const float* __restrict__ seed,
                                               float* __restrict__ ws, unsigned mask) {
  float a = seed[threadIdx.x & 7] * 1e-12f + 1.000001f;   // runtime, unfoldable
  const float b = 1.0000001f, c = 1e-9f;
  #pragma unroll 1
  for (int i = 0; i < 128; ++i) {
    #pragma unroll
    for (int j = 0; j < 64; ++j) a = fmaf(a, b, c);
  }
  const unsigned idx = (blockIdx.x * blockDim.x + threadIdx.x) & mask;
  ws[idx] = a;    // keep chain live; ws is scratch, never validated
}

// ============ real kernel (R11, unchanged) ============
__global__ __launch_bounds__(256) void hurst_ilp4(
    const float* __restrict__ ret, const float* __restrict__ W1,
    const float* __restrict__ b1,  const float* __restrict__ W2,
    const float* __restrict__ b2,  float* __restrict__ out) {
  __shared__ float srow[LROW];

  const int row = blockIdx.x;
  const float* __restrict__ rowp = ret + (size_t)row * TDIM;
  float* __restrict__ orow = out + (size_t)row * TDIM;

  {
    const int tid = threadIdx.x;
    #pragma unroll
    for (int it = 0; it < 3; ++it) {
      const int c = tid + it * 256;
      if (c < LROW / 8) {
        f32x8 f;
        if (c < TDIM / 8) {
          f32x4u a = *(const f32x4u*)(rowp + 8 * c);
          f32x4u b = *(const f32x4u*)(rowp + 8 * c + 4);
          f[0]=a[0]; f[1]=a[1]; f[2]=a[2]; f[3]=a[3];
          f[4]=b[0]; f[5]=b[1]; f[6]=b[2]; f[7]=b[3];
        } else {
          const float last = rowp[TDIM - 1];
          #pragma unroll
          for (int j = 0; j < 8; ++j) f[j] = last;
        }
        f32x4a lo = {f[0], f[1], f[2], f[3]};
        f32x4a hi = {f[4], f[5], f[6], f[7]};
        *(f32x4a*)(srow + 8 * c)     = lo;
        *(f32x4a*)(srow + 8 * c + 4) = hi;
      }
    }
  }

  Setup S = make_setup(W1, b1, W2, b2);
  __syncthreads();

  const int wv  = threadIdx.x >> 6;
  const int seg = wv * 1024;
  const float* __restrict__ lbase = srow + seg + S.n + 8 * S.g;

  #pragma unroll 1
  for (int q = 0; q < 8; ++q) {
    const float* qb = lbase + q * 128;

    bf16x8 bvA = cvt8(lds_ld8(qb));
    bf16x8 bvB = cvt8(lds_ld8(qb + 32));
    bf16x8 bvC = cvt8(lds_ld8(qb + 64));
    bf16x8 bvD = cvt8(lds_ld8(qb + 96));

    f32x16 aA = __builtin_amdgcn_mfma_f32_32x32x16_bf16(S.af, bvA, S.cinit, 0, 0, 0);
    f32x16 aB = __builtin_amdgcn_mfma_f32_32x32x16_bf16(S.af, bvB, S.cinit, 0, 0, 0);
    f32x16 aC = __builtin_amdgcn_mfma_f32_32x32x16_bf16(S.af, bvC, S.cinit, 0, 0, 0);
    f32x16 aD = __builtin_amdgcn_mfma_f32_32x32x16_bf16(S.af, bvD, S.cinit, 0, 0, 0);

    f32x2 sA0={0.f,0.f}, sA1={0.f,0.f}, sB0={0.f,0.f}, sB1={0.f,0.f};
    f32x2 sC0={0.f,0.f}, sC1={0.f,0.f}, sD0={0.f,0.f}, sD1={0.f,0.f};
    #pragma unroll
    for (int j = 0; j < 8; j += 2) {
      sA0 = __builtin_elementwise_fma(relu2(aA[2*j],   aA[2*j+1]), S.w2p[j],   sA0);
      sB0 = __builtin_elementwise_fma(relu2(aB[2*j],   aB[2*j+1]), S.w2p[j],   sB0);
      sC0 = __builtin_elementwise_fma(relu2(aC[2*j],   aC[2*j+1]), S.w2p[j],   sC0);
      sD0 = __builtin_elementwise_fma(relu2(aD[2*j],   aD[2*j+1]), S.w2p[j],   sD0);
      sA1 = __builtin_elementwise_fma(relu2(aA[2*j+2], aA[2*j+3]), S.w2p[j+1], sA1);
      sB1 = __builtin_elementwise_fma(relu2(aB[2*j+2], aB[2*j+3]), S.w2p[j+1], sB1);
      sC1 = __builtin_elementwise_fma(relu2(aC[2*j+2], aC[2*j+3]), S.w2p[j+1], sC1);
      sD1 = __builtin_elementwise_fma(relu2(aD[2*j+2], aD[2*j+3]), S.w2p[j+1], sD1);
    }
    f32x2 sA = sA0 + sA1, sB = sB0 + sB1, sC = sC0 + sC1, sD = sD0 + sD1;
    float PA = sA[0] + sA[1], PB = sB[0] + sB[1];
    float PC = sC[0] + sC[1], PD = sD[0] + sD[1];

    const float q0 = combine_halves(PA, PB, S.lid);
    const float q1 = combine_halves(PC, PD, S.lid);
    const float y0 = half_sigmoid(q0 + S.b2c);
    const float y1 = half_sigmoid(q1 + S.b2c);

    const int t0 = seg + q * 128 + S.lid;
    const int t1 = t0 + 64;
    orow[WINDOW + t0] = y0;
    if (t1 < TVALID) orow[WINDOW + t1] = y1;

    if (q == 0 && wv == 0) {
      const float yh = __shfl(y0, 0, 64);
      if (S.lid < WINDOW) orow[S.lid] = yh;
    }
  }
}

extern "C" void kernel_launch(void* const* d_in, const int* in_sizes, int n_in,
                              void* d_out, int out_size, void* d_ws, size_t ws_size,
                              hipStream_t stream) {
  const float* ret = (const float*)d_in[0];
  const float* W1  = (const float*)d_in[1];
  const float* b1  = (const float*)d_in[2];
  const float* W2  = (const float*)d_in[3];
  const float* b2  = (const float*)d_in[4];
  float* out = (float*)d_out;

  const int B = in_sizes[0] / TDIM;     // 2048
  dim3 block(256);
  dim3 grid(B);

  // --- calibration dispatch (scratch only; duration read from rocprof) ---
  if (ws_size >= 4096) {
    unsigned words = (unsigned)(ws_size / 4);
    unsigned mask = 1; while ((mask << 1) <= words && (mask << 1) != 0) mask <<= 1;
    mask -= 1;
    if (mask > 0x3FFFFu) mask = 0x3FFFFu;   // cap at 1 MB region
    hipLaunchKernelGGL(k_clock, grid, block, 0, stream,
                       ret, (float*)d_ws, mask);
  }

  // --- real kernel ---
  hipLaunchKernelGGL(hurst_ilp4, grid, block, 0, stream,
                     ret, W1, b1, W2, b2, out);
}